// Round 2
// baseline (873.652 us; speedup 1.0000x reference)
//
#include <hip/hip_runtime.h>
#include <hip/hip_bf16.h>

// Problem constants
#define B_   128
#define J_   2048
#define N_   32
#define D_   16
#define NS   4        // rotating partial copies of s (reduces atomic contention)

// ---------------------------------------------------------------------------
// Z: zero the NS s-partials (NS*65536 floats)
// ---------------------------------------------------------------------------
__global__ __launch_bounds__(256) void capsZ(float* __restrict__ s4) {
    int gid = blockIdx.x * 256 + threadIdx.x;
    s4[gid] = 0.0f;
}

// ---------------------------------------------------------------------------
// A: s[b,n,d] += sum_{j,p} W[n,j,d,p] * (c[b,n,j] * x[b,j,p])
//    LDS-free main loop. Block = (n, 64-j chunk), 256 thr = 4 waves.
//    Wave wv owns 16 consecutive j (W address wave-uniform -> scalar loads).
//    Lane covers b = lane and lane+64; acc[16][2] in VGPRs.
//    End: ds_add_f32 into 8KB LDS tile, then atomicAdd into s4[jc%NS].
// ---------------------------------------------------------------------------
__global__ __launch_bounds__(256, 4) void capsA(const float* __restrict__ W,
                                                const float* __restrict__ x,
                                                const float* __restrict__ blog,
                                                const float2* __restrict__ md,
                                                float* __restrict__ s4,
                                                int mode) {
    __shared__ float s_lds[D_ * B_];   // [16 d][128 b] = 8 KB
    const int t    = threadIdx.x;
    const int lane = t & 63;
    const int n    = blockIdx.x & 31;
    const int jc   = blockIdx.x >> 5;          // 0..31
    const int wv   = __builtin_amdgcn_readfirstlane(t >> 6);   // 0..3, uniform

    float acc[D_][2];
    #pragma unroll
    for (int d = 0; d < D_; ++d) { acc[d][0] = 0.f; acc[d][1] = 0.f; }

    const int jbase = jc * 64 + wv * 16;

    for (int jj = 0; jj < 16; ++jj) {
        const int j = jbase + jj;              // wave-uniform

        // x for b = lane, lane+64 (32B contiguous per b; lines reused over jj)
        const float4* xp0 = (const float4*)(x + ((size_t)lane * J_ + j) * 8);
        const float4* xp1 = (const float4*)(x + ((size_t)(lane + 64) * J_ + j) * 8);
        float4 xa = xp0[0], xb = xp0[1];
        float4 xe = xp1[0], xf = xp1[1];

        float c0, c1;
        if (mode == 0) {
            c0 = 1.0f / 32.0f; c1 = 1.0f / 32.0f;
        } else {
            float lg0 = blog[((size_t)lane * N_ + n) * J_ + j];
            float lg1 = blog[((size_t)(lane + 64) * N_ + n) * J_ + j];
            float2 m0 = md[(size_t)lane * J_ + j];
            float2 m1 = md[(size_t)(lane + 64) * J_ + j];
            c0 = __expf(lg0 - m0.x) * m0.y;
            c1 = __expf(lg1 - m1.x) * m1.y;
        }

        float x0[8], x1[8];
        x0[0]=xa.x*c0; x0[1]=xa.y*c0; x0[2]=xa.z*c0; x0[3]=xa.w*c0;
        x0[4]=xb.x*c0; x0[5]=xb.y*c0; x0[6]=xb.z*c0; x0[7]=xb.w*c0;
        x1[0]=xe.x*c1; x1[1]=xe.y*c1; x1[2]=xe.z*c1; x1[3]=xe.w*c1;
        x1[4]=xf.x*c1; x1[5]=xf.y*c1; x1[6]=xf.z*c1; x1[7]=xf.w*c1;

        // W row for this j: wave-uniform address -> scalar/merged loads
        const float4* wp4 = (const float4*)(W + ((size_t)n * J_ + j) * 128);
        #pragma unroll
        for (int d = 0; d < D_; ++d) {
            float4 wa = wp4[d * 2];
            float4 wb = wp4[d * 2 + 1];
            acc[d][0] = fmaf(wa.x, x0[0], acc[d][0]);
            acc[d][1] = fmaf(wa.x, x1[0], acc[d][1]);
            acc[d][0] = fmaf(wa.y, x0[1], acc[d][0]);
            acc[d][1] = fmaf(wa.y, x1[1], acc[d][1]);
            acc[d][0] = fmaf(wa.z, x0[2], acc[d][0]);
            acc[d][1] = fmaf(wa.z, x1[2], acc[d][1]);
            acc[d][0] = fmaf(wa.w, x0[3], acc[d][0]);
            acc[d][1] = fmaf(wa.w, x1[3], acc[d][1]);
            acc[d][0] = fmaf(wb.x, x0[4], acc[d][0]);
            acc[d][1] = fmaf(wb.x, x1[4], acc[d][1]);
            acc[d][0] = fmaf(wb.y, x0[5], acc[d][0]);
            acc[d][1] = fmaf(wb.y, x1[5], acc[d][1]);
            acc[d][0] = fmaf(wb.z, x0[6], acc[d][0]);
            acc[d][1] = fmaf(wb.z, x1[6], acc[d][1]);
            acc[d][0] = fmaf(wb.w, x0[7], acc[d][0]);
            acc[d][1] = fmaf(wb.w, x1[7], acc[d][1]);
        }
    }

    // ---- block-level combine: LDS atomic adds (conflict-free addressing) ----
    for (int i = t; i < D_ * B_; i += 256) s_lds[i] = 0.0f;
    __syncthreads();
    #pragma unroll
    for (int d = 0; d < D_; ++d) {
        atomicAdd(&s_lds[d * B_ + lane],      acc[d][0]);
        atomicAdd(&s_lds[d * B_ + lane + 64], acc[d][1]);
    }
    __syncthreads();
    float* sdst = s4 + (size_t)(jc & (NS - 1)) * (B_ * N_ * D_);
    for (int i = t; i < D_ * B_; i += 256) {
        int d = i >> 7, b = i & 127;
        atomicAdd(&sdst[(size_t)b * (N_ * D_) + n * D_ + d], s_lds[i]);
    }
}

// ---------------------------------------------------------------------------
// R: out[b,n,d] = squash(sum_NS s4 + bias)
// ---------------------------------------------------------------------------
__global__ __launch_bounds__(256) void capsR(const float* __restrict__ s4,
                                             const float* __restrict__ bias,
                                             float* __restrict__ out) {
    int gid = blockIdx.x * 256 + threadIdx.x;       // 65536
    int nd  = gid & 511;
    float sv = s4[gid] + s4[gid + 65536] + s4[gid + 2 * 65536] + s4[gid + 3 * 65536]
             + bias[nd];
    float sq = sv * sv;
    sq += __shfl_xor(sq, 1);
    sq += __shfl_xor(sq, 2);
    sq += __shfl_xor(sq, 4);
    sq += __shfl_xor(sq, 8);
    float scale = sq / (1.0f + sq) / sqrtf(sq + 1e-7f);
    out[gid] = scale * sv;
}

// ---------------------------------------------------------------------------
// B: blog[b,n,j] (+)= sum_p x[b,j,p] * (sum_d o[b,n,d]*W[n,j,d,p])
//    1-wave blocks. Thread = (j, d-half): W slice 8x8 in 64 VGPRs (read once,
//    coalesced). Per b: 2x float4 o + 2x float4 x, 72 fmac, shfl_xor(1).
// ---------------------------------------------------------------------------
__global__ __launch_bounds__(64, 4) void capsB(const float* __restrict__ W,
                                               const float* __restrict__ x,
                                               const float* __restrict__ o,
                                               float* __restrict__ blog,
                                               int accumulate) {
    const int t  = threadIdx.x;        // 0..63
    const int n  = blockIdx.x & 31;
    const int jt = blockIdx.x >> 5;    // 0..63
    const int jl = t >> 1;             // 0..31
    const int dh = t & 1;              // d-half
    const int j  = jt * 32 + jl;

    float w[8][8];
    const float* wp = W + (((size_t)n * J_ + j) * 16 + dh * 8) * 8;
    #pragma unroll
    for (int dd = 0; dd < 8; ++dd) {
        float4 a = *(const float4*)(wp + dd * 8);
        float4 b4 = *(const float4*)(wp + dd * 8 + 4);
        w[dd][0]=a.x;  w[dd][1]=a.y;  w[dd][2]=a.z;  w[dd][3]=a.w;
        w[dd][4]=b4.x; w[dd][5]=b4.y; w[dd][6]=b4.z; w[dd][7]=b4.w;
    }

    for (int b = 0; b < B_; ++b) {
        const float4* op = (const float4*)(o + ((size_t)b * N_ + n) * 16 + dh * 8);
        float4 o0 = op[0], o1 = op[1];
        float od[8] = {o0.x,o0.y,o0.z,o0.w,o1.x,o1.y,o1.z,o1.w};
        const float4* xp = (const float4*)(x + ((size_t)b * J_ + j) * 8);
        float4 xv0 = xp[0], xv1 = xp[1];
        float xv[8] = {xv0.x,xv0.y,xv0.z,xv0.w,xv1.x,xv1.y,xv1.z,xv1.w};
        float tt = 0.f;
        #pragma unroll
        for (int p = 0; p < 8; ++p) {
            float sp = 0.f;
            #pragma unroll
            for (int dd = 0; dd < 8; ++dd) sp = fmaf(w[dd][p], od[dd], sp);
            tt = fmaf(sp, xv[p], tt);
        }
        tt += __shfl_xor(tt, 1);
        if (dh == 0) {
            size_t addr = ((size_t)b * N_ + n) * J_ + j;
            blog[addr] = accumulate ? (blog[addr] + tt) : tt;
        }
    }
}

// ---------------------------------------------------------------------------
// D: per (b,j): m = max_n blog, invd = 1/sum_n exp(blog-m); also zero s4
//    grid: 1024 blocks * 256 = 262144 threads = NS*65536 exactly
// ---------------------------------------------------------------------------
__global__ __launch_bounds__(256) void capsD(const float* __restrict__ blog,
                                             float2* __restrict__ md,
                                             float* __restrict__ s4) {
    int gid = blockIdx.x * 256 + threadIdx.x;
    s4[gid] = 0.0f;                      // fused zero of all NS partials
    int b = gid >> 11;
    int j = gid & 2047;
    float v[32];
    float m = -1e30f;
    #pragma unroll
    for (int nn = 0; nn < 32; ++nn) {
        v[nn] = blog[((size_t)b * N_ + nn) * J_ + j];
        m = fmaxf(m, v[nn]);
    }
    float sum = 0.0f;
    #pragma unroll
    for (int nn = 0; nn < 32; ++nn) sum += __expf(v[nn] - m);
    md[gid] = make_float2(m, 1.0f / sum);
}

// ---------------------------------------------------------------------------
extern "C" void kernel_launch(void* const* d_in, const int* in_sizes, int n_in,
                              void* d_out, int out_size, void* d_ws, size_t ws_size,
                              hipStream_t stream) {
    const float* x    = (const float*)d_in[0];   // [128,2048,8]
    const float* W    = (const float*)d_in[1];   // [32,2048,16,8]
    const float* bias = (const float*)d_in[2];   // [32,16]
    float* out = (float*)d_out;                  // [128,32,16]

    float*  ws   = (float*)d_ws;
    float*  blog = ws;                                        // 33.55 MB
    float2* md   = (float2*)(ws + (size_t)B_ * N_ * J_);      // 2.1 MB
    float*  s4   = ws + (size_t)B_ * N_ * J_ + 2 * (size_t)B_ * J_;  // NS*65536 floats

    // ---- routing iteration 0 (c uniform) ----
    capsZ<<<dim3(NS * B_ * N_ * D_ / 256), dim3(256), 0, stream>>>(s4);
    capsA<<<dim3(N_ * 32), dim3(256), 0, stream>>>(W, x, blog, md, s4, 0);
    capsR<<<dim3(B_ * N_ * D_ / 256), dim3(256), 0, stream>>>(s4, bias, out);
    capsB<<<dim3(N_ * (J_ / 32)), dim3(64), 0, stream>>>(W, x, out, blog, 0);

    // ---- routing iteration 1 ----
    capsD<<<dim3(B_ * J_ / 256), dim3(256), 0, stream>>>(blog, md, s4);
    capsA<<<dim3(N_ * 32), dim3(256), 0, stream>>>(W, x, blog, md, s4, 1);
    capsR<<<dim3(B_ * N_ * D_ / 256), dim3(256), 0, stream>>>(s4, bias, out);
    capsB<<<dim3(N_ * (J_ / 32)), dim3(64), 0, stream>>>(W, x, out, blog, 1);

    // ---- routing iteration 2 (final) ----
    capsD<<<dim3(B_ * J_ / 256), dim3(256), 0, stream>>>(blog, md, s4);
    capsA<<<dim3(N_ * 32), dim3(256), 0, stream>>>(W, x, blog, md, s4, 1);
    capsR<<<dim3(B_ * N_ * D_ / 256), dim3(256), 0, stream>>>(s4, bias, out);
}

// Round 3
// 580.872 us; speedup vs baseline: 1.5040x; 1.5040x over previous
//
#include <hip/hip_runtime.h>
#include <hip/hip_bf16.h>

// Problem constants
#define B_   128
#define J_   2048
#define N_   32
#define D_   16
#define NS   4        // rotating partial copies of s (reduces atomic contention)

// Workspace layout (float offsets):
//  xT    [0, 2097152)            xT[(j*8+p)*128 + b]          8 MB fp32
//  blogT [2097152, 6291456)      blogT[(n*J+j)*128 + b]      16 MB bf16
//  mdT   [6291456, 6815744)      mdT[j*128 + b] float2        2 MB
//  s4    [6815744, 7077888)      NS copies of s[b][n][d]      1 MB
// total 28.3 MB

// ---------------------------------------------------------------------------
// T: xT[(j*8+p)*128 + b] = x[b][j][p]   (LDS tile transpose, 512 blocks)
// ---------------------------------------------------------------------------
__global__ __launch_bounds__(256) void capsT(const float* __restrict__ x,
                                             float* __restrict__ xT) {
    __shared__ float tile[32][129];
    const int t   = threadIdx.x;
    const int jp0 = blockIdx.x * 32;             // 512 blocks cover 16384 jp
    for (int idx = t; idx < 128 * 32; idx += 256) {
        int b = idx >> 5, k = idx & 31;
        tile[k][b] = x[(size_t)b * 16384 + jp0 + k];
    }
    __syncthreads();
    for (int idx = t; idx < 128 * 32; idx += 256) {
        int k = idx >> 7, b = idx & 127;
        xT[(size_t)(jp0 + k) * 128 + b] = tile[k][b];
    }
}

// ---------------------------------------------------------------------------
// Z: zero the NS s-partials
// ---------------------------------------------------------------------------
__global__ __launch_bounds__(256) void capsZ(float* __restrict__ s4) {
    int gid = blockIdx.x * 256 + threadIdx.x;
    s4[gid] = 0.0f;
}

// ---------------------------------------------------------------------------
// A: s[b,n,d] += sum_{j,p} W[n,j,d,p] * (c[b,n,j] * x[b,j,p])
//    Block = (n, 64-j chunk), 256 thr = 4 waves x 16 j. Lane owns b=lane,lane+64.
//    All per-lane loads coalesced via xT/blogT/mdT; W loads wave-uniform (SGPR).
//    XCD swizzle: same-jc blocks (sharing xT rows) colocate on one XCD.
// ---------------------------------------------------------------------------
__global__ __launch_bounds__(256, 4) void capsA(const float* __restrict__ W,
                                                const float* __restrict__ xT,
                                                const __hip_bfloat16* __restrict__ blogT,
                                                const float2* __restrict__ mdT,
                                                float* __restrict__ s4,
                                                int mode) {
    __shared__ float s_lds[D_ * B_];   // [16 d][128 b] = 8 KB
    const int t    = threadIdx.x;
    const int lane = t & 63;
    const int i    = blockIdx.x;                         // 0..1023
    const int jc   = (i & 7) + 8 * (i >> 8);             // 0..31 (XCD-grouped)
    const int n    = (i >> 3) & 31;
    const int wv   = __builtin_amdgcn_readfirstlane(t >> 6);
    const int jbase = jc * 64 + wv * 16;

    float acc[D_][2];
    #pragma unroll
    for (int d = 0; d < D_; ++d) { acc[d][0] = 0.f; acc[d][1] = 0.f; }

    for (int jj = 0; jj < 16; ++jj) {
        const int j = jbase + jj;                        // wave-uniform

        float c0 = 1.0f / 32.0f, c1 = 1.0f / 32.0f;
        if (mode) {
            float lg0 = __bfloat162float(blogT[((size_t)n * J_ + j) * B_ + lane]);
            float lg1 = __bfloat162float(blogT[((size_t)n * J_ + j) * B_ + lane + 64]);
            float2 m0 = mdT[(size_t)j * B_ + lane];
            float2 m1 = mdT[(size_t)j * B_ + lane + 64];
            c0 = __expf(lg0 - m0.x) * m0.y;
            c1 = __expf(lg1 - m1.x) * m1.y;
        }

        const float* xr = xT + (size_t)j * 8 * B_;
        float x0[8], x1[8];
        #pragma unroll
        for (int p = 0; p < 8; ++p) {
            x0[p] = xr[p * B_ + lane] * c0;              // coalesced 256B
            x1[p] = xr[p * B_ + lane + 64] * c1;
        }

        const float4* wp4 = (const float4*)(W + ((size_t)n * J_ + j) * 128);
        #pragma unroll
        for (int d = 0; d < D_; ++d) {
            float4 wa = wp4[d * 2];
            float4 wb = wp4[d * 2 + 1];
            acc[d][0] = fmaf(wa.x, x0[0], acc[d][0]);
            acc[d][1] = fmaf(wa.x, x1[0], acc[d][1]);
            acc[d][0] = fmaf(wa.y, x0[1], acc[d][0]);
            acc[d][1] = fmaf(wa.y, x1[1], acc[d][1]);
            acc[d][0] = fmaf(wa.z, x0[2], acc[d][0]);
            acc[d][1] = fmaf(wa.z, x1[2], acc[d][1]);
            acc[d][0] = fmaf(wa.w, x0[3], acc[d][0]);
            acc[d][1] = fmaf(wa.w, x1[3], acc[d][1]);
            acc[d][0] = fmaf(wb.x, x0[4], acc[d][0]);
            acc[d][1] = fmaf(wb.x, x1[4], acc[d][1]);
            acc[d][0] = fmaf(wb.y, x0[5], acc[d][0]);
            acc[d][1] = fmaf(wb.y, x1[5], acc[d][1]);
            acc[d][0] = fmaf(wb.z, x0[6], acc[d][0]);
            acc[d][1] = fmaf(wb.z, x1[6], acc[d][1]);
            acc[d][0] = fmaf(wb.w, x0[7], acc[d][0]);
            acc[d][1] = fmaf(wb.w, x1[7], acc[d][1]);
        }
    }

    // ---- block-level combine (proven conflict-free in round 2) ----
    for (int q = t; q < D_ * B_; q += 256) s_lds[q] = 0.0f;
    __syncthreads();
    #pragma unroll
    for (int d = 0; d < D_; ++d) {
        atomicAdd(&s_lds[d * B_ + lane],      acc[d][0]);
        atomicAdd(&s_lds[d * B_ + lane + 64], acc[d][1]);
    }
    __syncthreads();
    float* sdst = s4 + (size_t)(jc & (NS - 1)) * (B_ * N_ * D_);
    for (int q = t; q < D_ * B_; q += 256) {
        int d = q >> 7, b = q & 127;
        atomicAdd(&sdst[(size_t)b * (N_ * D_) + n * D_ + d], s_lds[q]);
    }
}

// ---------------------------------------------------------------------------
// R: out[b,n,d] = squash(sum_NS s4 + bias)
// ---------------------------------------------------------------------------
__global__ __launch_bounds__(256) void capsR(const float* __restrict__ s4,
                                             const float* __restrict__ bias,
                                             float* __restrict__ out) {
    int gid = blockIdx.x * 256 + threadIdx.x;       // 65536: b*512 + n*16 + d
    int nd  = gid & 511;
    float sv = s4[gid] + s4[gid + 65536] + s4[gid + 2 * 65536] + s4[gid + 3 * 65536]
             + bias[nd];
    float sq = sv * sv;
    sq += __shfl_xor(sq, 1);
    sq += __shfl_xor(sq, 2);
    sq += __shfl_xor(sq, 4);
    sq += __shfl_xor(sq, 8);
    float scale = sq / (1.0f + sq) / sqrtf(sq + 1e-7f);
    out[gid] = scale * sv;
}

// ---------------------------------------------------------------------------
// B: blogT[n,j,b] (+)= sum_p x[b,j,p] * (sum_d o[b,n,d]*W[n,j,d,p])
//    Same geometry/swizzle as capsA. o in 32 VGPRs per thread (2 b-halves).
//    Coalesced xT reads and bf16 blogT writes.
// ---------------------------------------------------------------------------
__global__ __launch_bounds__(256, 4) void capsB(const float* __restrict__ W,
                                                const float* __restrict__ xT,
                                                const float* __restrict__ o,
                                                __hip_bfloat16* __restrict__ blogT,
                                                int accumulate) {
    const int t    = threadIdx.x;
    const int lane = t & 63;
    const int i    = blockIdx.x;                         // 0..1023
    const int jc   = (i & 7) + 8 * (i >> 8);
    const int n    = (i >> 3) & 31;
    const int wv   = __builtin_amdgcn_readfirstlane(t >> 6);
    const int jbase = jc * 64 + wv * 16;

    float o0[16], o1[16];
    {
        const float4* p0 = (const float4*)(o + ((size_t)lane * N_ + n) * 16);
        const float4* p1 = (const float4*)(o + ((size_t)(lane + 64) * N_ + n) * 16);
        #pragma unroll
        for (int q = 0; q < 4; ++q) {
            float4 a = p0[q];
            o0[q*4] = a.x; o0[q*4+1] = a.y; o0[q*4+2] = a.z; o0[q*4+3] = a.w;
            float4 b = p1[q];
            o1[q*4] = b.x; o1[q*4+1] = b.y; o1[q*4+2] = b.z; o1[q*4+3] = b.w;
        }
    }

    for (int jj = 0; jj < 16; ++jj) {
        const int j = jbase + jj;                        // wave-uniform
        float g0[8] = {0,0,0,0,0,0,0,0};
        float g1[8] = {0,0,0,0,0,0,0,0};
        const float4* wp4 = (const float4*)(W + ((size_t)n * J_ + j) * 128);
        #pragma unroll
        for (int d = 0; d < D_; ++d) {
            float4 wa = wp4[d * 2];
            float4 wb = wp4[d * 2 + 1];
            g0[0] = fmaf(wa.x, o0[d], g0[0]); g1[0] = fmaf(wa.x, o1[d], g1[0]);
            g0[1] = fmaf(wa.y, o0[d], g0[1]); g1[1] = fmaf(wa.y, o1[d], g1[1]);
            g0[2] = fmaf(wa.z, o0[d], g0[2]); g1[2] = fmaf(wa.z, o1[d], g1[2]);
            g0[3] = fmaf(wa.w, o0[d], g0[3]); g1[3] = fmaf(wa.w, o1[d], g1[3]);
            g0[4] = fmaf(wb.x, o0[d], g0[4]); g1[4] = fmaf(wb.x, o1[d], g1[4]);
            g0[5] = fmaf(wb.y, o0[d], g0[5]); g1[5] = fmaf(wb.y, o1[d], g1[5]);
            g0[6] = fmaf(wb.z, o0[d], g0[6]); g1[6] = fmaf(wb.z, o1[d], g1[6]);
            g0[7] = fmaf(wb.w, o0[d], g0[7]); g1[7] = fmaf(wb.w, o1[d], g1[7]);
        }
        const float* xr = xT + (size_t)j * 8 * B_;
        float t0 = 0.f, t1 = 0.f;
        #pragma unroll
        for (int p = 0; p < 8; ++p) {
            t0 = fmaf(g0[p], xr[p * B_ + lane], t0);
            t1 = fmaf(g1[p], xr[p * B_ + lane + 64], t1);
        }
        size_t a0 = ((size_t)n * J_ + j) * B_ + lane;
        if (accumulate) {
            t0 += __bfloat162float(blogT[a0]);
            t1 += __bfloat162float(blogT[a0 + 64]);
        }
        blogT[a0]      = __float2bfloat16(t0);
        blogT[a0 + 64] = __float2bfloat16(t1);
    }
}

// ---------------------------------------------------------------------------
// D: per (j,b): m = max_n blogT, inv = 1/sum_n exp(blogT-m); also zero s4
//    gid = j*128 + b; all reads/writes coalesced.
// ---------------------------------------------------------------------------
__global__ __launch_bounds__(256) void capsD(const __hip_bfloat16* __restrict__ blogT,
                                             float2* __restrict__ mdT,
                                             float* __restrict__ s4) {
    int gid = blockIdx.x * 256 + threadIdx.x;   // 262144 = J_*B_ = NS*65536
    s4[gid] = 0.0f;                             // fused zero of all NS partials
    float v[32];
    float m = -1e30f;
    #pragma unroll
    for (int nn = 0; nn < 32; ++nn) {
        v[nn] = __bfloat162float(blogT[(size_t)nn * (J_ * B_) + gid]);
        m = fmaxf(m, v[nn]);
    }
    float sum = 0.0f;
    #pragma unroll
    for (int nn = 0; nn < 32; ++nn) sum += __expf(v[nn] - m);
    mdT[gid] = make_float2(m, 1.0f / sum);
}

// ---------------------------------------------------------------------------
extern "C" void kernel_launch(void* const* d_in, const int* in_sizes, int n_in,
                              void* d_out, int out_size, void* d_ws, size_t ws_size,
                              hipStream_t stream) {
    const float* x    = (const float*)d_in[0];   // [128,2048,8]
    const float* W    = (const float*)d_in[1];   // [32,2048,16,8]
    const float* bias = (const float*)d_in[2];   // [32,16]
    float* out = (float*)d_out;                  // [128,32,16]

    float* ws = (float*)d_ws;
    float*           xT    = ws;                                   // 8 MB
    __hip_bfloat16*  blogT = (__hip_bfloat16*)(ws + 2097152);      // 16 MB bf16
    float2*          mdT   = (float2*)(ws + 2097152 + 4194304);    // 2 MB
    float*           s4    = ws + 2097152 + 4194304 + 524288;      // 1 MB

    dim3 blk(256);

    capsT<<<dim3(512), blk, 0, stream>>>(x, xT);

    // ---- routing iteration 0 (c uniform) ----
    capsZ<<<dim3(NS * B_ * N_ * D_ / 256), blk, 0, stream>>>(s4);
    capsA<<<dim3(1024), blk, 0, stream>>>(W, xT, blogT, mdT, s4, 0);
    capsR<<<dim3(B_ * N_ * D_ / 256), blk, 0, stream>>>(s4, bias, out);
    capsB<<<dim3(1024), blk, 0, stream>>>(W, xT, out, blogT, 0);

    // ---- routing iteration 1 ----
    capsD<<<dim3(J_ * B_ / 256), blk, 0, stream>>>(blogT, mdT, s4);
    capsA<<<dim3(1024), blk, 0, stream>>>(W, xT, blogT, mdT, s4, 1);
    capsR<<<dim3(B_ * N_ * D_ / 256), blk, 0, stream>>>(s4, bias, out);
    capsB<<<dim3(1024), blk, 0, stream>>>(W, xT, out, blogT, 1);

    // ---- routing iteration 2 (final) ----
    capsD<<<dim3(J_ * B_ / 256), blk, 0, stream>>>(blogT, mdT, s4);
    capsA<<<dim3(1024), blk, 0, stream>>>(W, xT, blogT, mdT, s4, 1);
    capsR<<<dim3(B_ * N_ * D_ / 256), blk, 0, stream>>>(s4, bias, out);
}

// Round 4
// 453.748 us; speedup vs baseline: 1.9254x; 1.2802x over previous
//
#include <hip/hip_runtime.h>
#include <hip/hip_bf16.h>

// Problem constants
#define B_   128
#define J_   2048
#define N_   32
#define D_   16
#define NJC  32       // j-chunks (64 j each); one s-partial per chunk

// Workspace layout (float offsets):
//  xT     [0, 2097152)            xT[(j*8+p)*128 + b]          8 MB fp32
//  blogT  [2097152, 6291456)      blogT[(n*J+j)*128 + b]      16 MB bf16
//  mdT    [6291456, 6815744)      mdT[j*128 + b] float2        2 MB
//  s_part [6815744, 8912896)      [jc][b*512+n*16+d]           8 MB fp32
// total 35.7 MB

// ---------------------------------------------------------------------------
// T: xT[(j*8+p)*128 + b] = x[b][j][p]   (LDS tile transpose, 512 blocks)
// ---------------------------------------------------------------------------
__global__ __launch_bounds__(256) void capsT(const float* __restrict__ x,
                                             float* __restrict__ xT) {
    __shared__ float tile[32][129];
    const int t   = threadIdx.x;
    const int jp0 = blockIdx.x * 32;
    for (int idx = t; idx < 128 * 32; idx += 256) {
        int b = idx >> 5, k = idx & 31;
        tile[k][b] = x[(size_t)b * 16384 + jp0 + k];
    }
    __syncthreads();
    for (int idx = t; idx < 128 * 32; idx += 256) {
        int k = idx >> 7, b = idx & 127;
        xT[(size_t)(jp0 + k) * 128 + b] = tile[k][b];
    }
}

// ---------------------------------------------------------------------------
// A: s_part[jc][b,n,d] = sum_{j in chunk,p} W[n,j,d,p] * (c[b,n,j]*x[b,j,p])
//    Block = (n, jc of 64 j), 512 thr = 8 waves x 8 j. Lane owns b=lane,lane+64.
//    Per-lane loads coalesced (xT/blogT/mdT); W loads wave-uniform -> SGPRs.
//    8 waves/SIMD for latency hiding. No global atomics: per-jc partials.
// ---------------------------------------------------------------------------
__global__ __launch_bounds__(512, 8) void capsA(const float* __restrict__ W,
                                                const float* __restrict__ xT,
                                                const __hip_bfloat16* __restrict__ blogT,
                                                const float2* __restrict__ mdT,
                                                float* __restrict__ s_part,
                                                int mode) {
    __shared__ float s_lds[D_ * B_];   // [16 d][128 b] = 8 KB
    const int t    = threadIdx.x;
    const int lane = t & 63;
    const int i    = blockIdx.x;                         // 0..1023
    const int jc   = (i & 7) + 8 * (i >> 8);             // 0..31 (XCD-grouped)
    const int n    = (i >> 3) & 31;
    const int wv   = __builtin_amdgcn_readfirstlane(t >> 6);   // 0..7
    const int jbase = jc * 64 + wv * 8;

    float acc[D_][2];
    #pragma unroll
    for (int d = 0; d < D_; ++d) { acc[d][0] = 0.f; acc[d][1] = 0.f; }

    for (int jj = 0; jj < 8; ++jj) {
        const int j = jbase + jj;                        // wave-uniform

        float c0 = 1.0f / 32.0f, c1 = 1.0f / 32.0f;
        if (mode) {
            float lg0 = __bfloat162float(blogT[((size_t)n * J_ + j) * B_ + lane]);
            float lg1 = __bfloat162float(blogT[((size_t)n * J_ + j) * B_ + lane + 64]);
            float2 m0 = mdT[(size_t)j * B_ + lane];
            float2 m1 = mdT[(size_t)j * B_ + lane + 64];
            c0 = __expf(lg0 - m0.x) * m0.y;
            c1 = __expf(lg1 - m1.x) * m1.y;
        }

        const float* xr = xT + (size_t)j * 8 * B_;
        float x0[8], x1[8];
        #pragma unroll
        for (int p = 0; p < 8; ++p) {
            x0[p] = xr[p * B_ + lane] * c0;              // coalesced 256B
            x1[p] = xr[p * B_ + lane + 64] * c1;
        }

        const float4* wp4 = (const float4*)(W + ((size_t)n * J_ + j) * 128);
        #pragma unroll
        for (int d = 0; d < D_; ++d) {
            float4 wa = wp4[d * 2];
            float4 wb = wp4[d * 2 + 1];
            acc[d][0] = fmaf(wa.x, x0[0], acc[d][0]);
            acc[d][1] = fmaf(wa.x, x1[0], acc[d][1]);
            acc[d][0] = fmaf(wa.y, x0[1], acc[d][0]);
            acc[d][1] = fmaf(wa.y, x1[1], acc[d][1]);
            acc[d][0] = fmaf(wa.z, x0[2], acc[d][0]);
            acc[d][1] = fmaf(wa.z, x1[2], acc[d][1]);
            acc[d][0] = fmaf(wa.w, x0[3], acc[d][0]);
            acc[d][1] = fmaf(wa.w, x1[3], acc[d][1]);
            acc[d][0] = fmaf(wb.x, x0[4], acc[d][0]);
            acc[d][1] = fmaf(wb.x, x1[4], acc[d][1]);
            acc[d][0] = fmaf(wb.y, x0[5], acc[d][0]);
            acc[d][1] = fmaf(wb.y, x1[5], acc[d][1]);
            acc[d][0] = fmaf(wb.z, x0[6], acc[d][0]);
            acc[d][1] = fmaf(wb.z, x1[6], acc[d][1]);
            acc[d][0] = fmaf(wb.w, x0[7], acc[d][0]);
            acc[d][1] = fmaf(wb.w, x1[7], acc[d][1]);
        }
    }

    // ---- block-level combine: LDS atomics then one coalesced partial write ----
    for (int q = t; q < D_ * B_; q += 512) s_lds[q] = 0.0f;
    __syncthreads();
    #pragma unroll
    for (int d = 0; d < D_; ++d) {
        atomicAdd(&s_lds[d * B_ + lane],      acc[d][0]);
        atomicAdd(&s_lds[d * B_ + lane + 64], acc[d][1]);
    }
    __syncthreads();
    float* sdst = s_part + (size_t)jc * (B_ * N_ * D_);
    for (int q = t; q < D_ * B_; q += 512) {
        int b = q >> 4, d = q & 15;
        sdst[(size_t)b * (N_ * D_) + n * D_ + d] = s_lds[d * B_ + b];
    }
}

// ---------------------------------------------------------------------------
// R: out[b,n,d] = squash(sum_jc s_part + bias)  (coalesced partial reads)
// ---------------------------------------------------------------------------
__global__ __launch_bounds__(256) void capsR(const float* __restrict__ s_part,
                                             const float* __restrict__ bias,
                                             float* __restrict__ out) {
    int gid = blockIdx.x * 256 + threadIdx.x;       // 65536: b*512 + n*16 + d
    float sv = bias[gid & 511];
    #pragma unroll
    for (int jc = 0; jc < NJC; ++jc)
        sv += s_part[(size_t)jc * 65536 + gid];
    float sq = sv * sv;
    sq += __shfl_xor(sq, 1);
    sq += __shfl_xor(sq, 2);
    sq += __shfl_xor(sq, 4);
    sq += __shfl_xor(sq, 8);
    float scale = sq / (1.0f + sq) / sqrtf(sq + 1e-7f);
    out[gid] = scale * sv;
}

// ---------------------------------------------------------------------------
// B: blogT[n,j,b] (+)= sum_p x[b,j,p] * (sum_d o[b,n,d]*W[n,j,d,p])
//    Same geometry as capsA (512 thr, 8 waves x 8 j). o in 32 VGPRs.
// ---------------------------------------------------------------------------
__global__ __launch_bounds__(512, 8) void capsB(const float* __restrict__ W,
                                                const float* __restrict__ xT,
                                                const float* __restrict__ o,
                                                __hip_bfloat16* __restrict__ blogT,
                                                int accumulate) {
    const int t    = threadIdx.x;
    const int lane = t & 63;
    const int i    = blockIdx.x;                         // 0..1023
    const int jc   = (i & 7) + 8 * (i >> 8);
    const int n    = (i >> 3) & 31;
    const int wv   = __builtin_amdgcn_readfirstlane(t >> 6);
    const int jbase = jc * 64 + wv * 8;

    float o0[16], o1[16];
    {
        const float4* p0 = (const float4*)(o + ((size_t)lane * N_ + n) * 16);
        const float4* p1 = (const float4*)(o + ((size_t)(lane + 64) * N_ + n) * 16);
        #pragma unroll
        for (int q = 0; q < 4; ++q) {
            float4 a = p0[q];
            o0[q*4] = a.x; o0[q*4+1] = a.y; o0[q*4+2] = a.z; o0[q*4+3] = a.w;
            float4 b = p1[q];
            o1[q*4] = b.x; o1[q*4+1] = b.y; o1[q*4+2] = b.z; o1[q*4+3] = b.w;
        }
    }

    for (int jj = 0; jj < 8; ++jj) {
        const int j = jbase + jj;                        // wave-uniform
        float g0[8] = {0,0,0,0,0,0,0,0};
        float g1[8] = {0,0,0,0,0,0,0,0};
        const float4* wp4 = (const float4*)(W + ((size_t)n * J_ + j) * 128);
        #pragma unroll
        for (int d = 0; d < D_; ++d) {
            float4 wa = wp4[d * 2];
            float4 wb = wp4[d * 2 + 1];
            g0[0] = fmaf(wa.x, o0[d], g0[0]); g1[0] = fmaf(wa.x, o1[d], g1[0]);
            g0[1] = fmaf(wa.y, o0[d], g0[1]); g1[1] = fmaf(wa.y, o1[d], g1[1]);
            g0[2] = fmaf(wa.z, o0[d], g0[2]); g1[2] = fmaf(wa.z, o1[d], g1[2]);
            g0[3] = fmaf(wa.w, o0[d], g0[3]); g1[3] = fmaf(wa.w, o1[d], g1[3]);
            g0[4] = fmaf(wb.x, o0[d], g0[4]); g1[4] = fmaf(wb.x, o1[d], g1[4]);
            g0[5] = fmaf(wb.y, o0[d], g0[5]); g1[5] = fmaf(wb.y, o1[d], g1[5]);
            g0[6] = fmaf(wb.z, o0[d], g0[6]); g1[6] = fmaf(wb.z, o1[d], g1[6]);
            g0[7] = fmaf(wb.w, o0[d], g0[7]); g1[7] = fmaf(wb.w, o1[d], g1[7]);
        }
        const float* xr = xT + (size_t)j * 8 * B_;
        float t0 = 0.f, t1 = 0.f;
        #pragma unroll
        for (int p = 0; p < 8; ++p) {
            t0 = fmaf(g0[p], xr[p * B_ + lane], t0);
            t1 = fmaf(g1[p], xr[p * B_ + lane + 64], t1);
        }
        size_t a0 = ((size_t)n * J_ + j) * B_ + lane;
        if (accumulate) {
            t0 += __bfloat162float(blogT[a0]);
            t1 += __bfloat162float(blogT[a0 + 64]);
        }
        blogT[a0]      = __float2bfloat16(t0);
        blogT[a0 + 64] = __float2bfloat16(t1);
    }
}

// ---------------------------------------------------------------------------
// D: per (j,b): m = max_n blogT, inv = 1/sum_n exp(blogT-m)
// ---------------------------------------------------------------------------
__global__ __launch_bounds__(256) void capsD(const __hip_bfloat16* __restrict__ blogT,
                                             float2* __restrict__ mdT) {
    int gid = blockIdx.x * 256 + threadIdx.x;   // 262144 = J_*B_
    float v[32];
    float m = -1e30f;
    #pragma unroll
    for (int nn = 0; nn < 32; ++nn) {
        v[nn] = __bfloat162float(blogT[(size_t)nn * (J_ * B_) + gid]);
        m = fmaxf(m, v[nn]);
    }
    float sum = 0.0f;
    #pragma unroll
    for (int nn = 0; nn < 32; ++nn) sum += __expf(v[nn] - m);
    mdT[gid] = make_float2(m, 1.0f / sum);
}

// ---------------------------------------------------------------------------
extern "C" void kernel_launch(void* const* d_in, const int* in_sizes, int n_in,
                              void* d_out, int out_size, void* d_ws, size_t ws_size,
                              hipStream_t stream) {
    const float* x    = (const float*)d_in[0];   // [128,2048,8]
    const float* W    = (const float*)d_in[1];   // [32,2048,16,8]
    const float* bias = (const float*)d_in[2];   // [32,16]
    float* out = (float*)d_out;                  // [128,32,16]

    float* ws = (float*)d_ws;
    float*           xT     = ws;                                   // 8 MB
    __hip_bfloat16*  blogT  = (__hip_bfloat16*)(ws + 2097152);      // 16 MB bf16
    float2*          mdT    = (float2*)(ws + 2097152 + 4194304);    // 2 MB
    float*           s_part = ws + 2097152 + 4194304 + 524288;      // 8 MB

    dim3 b256(256), b512(512);

    capsT<<<dim3(512), b256, 0, stream>>>(x, xT);

    // ---- routing iteration 0 (c uniform) ----
    capsA<<<dim3(1024), b512, 0, stream>>>(W, xT, blogT, mdT, s_part, 0);
    capsR<<<dim3(256), b256, 0, stream>>>(s_part, bias, out);
    capsB<<<dim3(1024), b512, 0, stream>>>(W, xT, out, blogT, 0);

    // ---- routing iteration 1 ----
    capsD<<<dim3(1024), b256, 0, stream>>>(blogT, mdT);
    capsA<<<dim3(1024), b512, 0, stream>>>(W, xT, blogT, mdT, s_part, 1);
    capsR<<<dim3(256), b256, 0, stream>>>(s_part, bias, out);
    capsB<<<dim3(1024), b512, 0, stream>>>(W, xT, out, blogT, 1);

    // ---- routing iteration 2 (final) ----
    capsD<<<dim3(1024), b256, 0, stream>>>(blogT, mdT);
    capsA<<<dim3(1024), b512, 0, stream>>>(W, xT, blogT, mdT, s_part, 1);
    capsR<<<dim3(256), b256, 0, stream>>>(s_part, bias, out);
}